// Round 8
// baseline (304.865 us; speedup 1.0000x reference)
//
#include <hip/hip_runtime.h>

// GCN: h1 = relu(GCNConv(x,W1,b1)); s1 = pool(h1); h2 = relu(GCNConv(h1,W2,b2)); s2 = pool(h2)
// out = [h2 (N*64) | per-graph rows [s1(64) s2(64)] (G*128)]
// batch is SORTED -> pooling is contiguous-range segment sum (no atomics).
// CSR build is bucketed (128 nodes/bucket); all random writes stay in LDS.
// Gather buffer g is bf16 (r7: halved k_agg FETCH 147->69MB). CSR rows are
// padded to 8-multiples with phantom node N (zero row) so k_agg's gather
// loop is unconditional; col indices are broadcast-loaded as int4 and moved
// to SGPRs (readfirstlane) so gather addressing runs in SALU.

#define FDIM 64
#define BSHIFT 7                 // 128 nodes per bucket
#define MAXNB 1024               // max buckets supported (N <= 131072)
#define BCAP 4096                // LDS capacity for one bucket's padded col region

__device__ __forceinline__ unsigned short f2bf(float f) {   // RNE
    union { float f; unsigned int u; } a; a.f = f;
    unsigned int u = a.u;
    unsigned int r = u + 0x7fffu + ((u >> 16) & 1u);
    return (unsigned short)(r >> 16);
}
__device__ __forceinline__ float bf2f(unsigned short s) {
    union { unsigned int u; float f; } a; a.u = ((unsigned int)s) << 16;
    return a.f;
}

// ---- pass 1: bucket histogram (LDS-privatized) ----
__global__ __launch_bounds__(256) void k_hist(const int* __restrict__ dst, int E, int NB,
                                              int* __restrict__ bucketCnt) {
    __shared__ int h[MAXNB];
    for (int i = threadIdx.x; i < NB; i += 256) h[i] = 0;
    __syncthreads();
    for (int e = blockIdx.x * blockDim.x + threadIdx.x; e < E; e += gridDim.x * blockDim.x)
        atomicAdd(&h[dst[e] >> BSHIFT], 1);
    __syncthreads();
    for (int i = threadIdx.x; i < NB; i += 256) {
        int c = h[i];
        if (c) atomicAdd(&bucketCnt[i], c);
    }
}

// ---- pass 2: scan bucket counts -> bucketStart[NB+1]; init bucketFill ----
__global__ __launch_bounds__(1024) void k_bscan(const int* __restrict__ bucketCnt, int NB, int E,
                                                int* __restrict__ bucketStart,
                                                int* __restrict__ bucketFill) {
    __shared__ int sm[MAXNB];
    int t = threadIdx.x;
    int v = (t < NB) ? bucketCnt[t] : 0;
    sm[t] = v;
    __syncthreads();
    for (int off = 1; off < MAXNB; off <<= 1) {
        int u = (t >= off) ? sm[t - off] : 0;
        __syncthreads();
        sm[t] += u;
        __syncthreads();
    }
    if (t < NB) {
        int ex = sm[t] - v;
        bucketStart[t] = ex;
        bucketFill[t] = ex;
    }
    if (t == 0) bucketStart[NB] = E;
}

// ---- pass 3: scatter packed (dloc<<17 | src) into bucket-grouped ebuf ----
// (src < 2^17 required: N = 100000 fits.)
__global__ __launch_bounds__(256) void k_bscat(const int* __restrict__ src,
                                               const int* __restrict__ dst, int E, int NB,
                                               int* __restrict__ bucketFill,
                                               unsigned int* __restrict__ ebuf) {
    __shared__ int hist[MAXNB];
    __shared__ int base[MAXNB];
    for (int i = threadIdx.x; i < NB; i += 256) hist[i] = 0;
    __syncthreads();
    int e0 = blockIdx.x * 4096;
    int s[16], d[16], r[16];
#pragma unroll
    for (int k = 0; k < 16; k++) {
        int e = e0 + k * 256 + threadIdx.x;
        bool valid = e < E;
        s[k] = valid ? src[e] : 0;
        d[k] = valid ? dst[e] : 0;
        r[k] = valid ? atomicAdd(&hist[d[k] >> BSHIFT], 1) : 0;
    }
    __syncthreads();
    for (int i = threadIdx.x; i < NB; i += 256) {
        int c = hist[i];
        base[i] = c ? atomicAdd(&bucketFill[i], c) : 0;
    }
    __syncthreads();
#pragma unroll
    for (int k = 0; k < 16; k++) {
        int e = e0 + k * 256 + threadIdx.x;
        if (e < E)
            ebuf[base[d[k] >> BSHIFT] + r[k]] =
                (unsigned int)s[k] | ((unsigned int)(d[k] & 127) << 17);
    }
}

// ---- pass 4: per-bucket padded-CSR finalize, entirely in LDS ----
// Each node's col row padded to a multiple of 8 with phantom index N.
// Bucket b's padded region starts at align8(bucketStart[b]) + b*1024
// (max padding/bucket = 128*7 + 7 < 1024, so regions never collide).
__global__ __launch_bounds__(256) void k_bsort(const unsigned int* __restrict__ ebuf,
                                               const int* __restrict__ bucketStart, int N,
                                               int* __restrict__ row_ptr,
                                               int* __restrict__ row_blocks,
                                               int* __restrict__ col,
                                               float* __restrict__ dinv) {
    __shared__ int cntL[128];
    __shared__ int scanL[128];
    __shared__ int fillL[128];
    __shared__ int colL[BCAP];
    __shared__ int padT;
    int b = blockIdx.x;
    int n0 = b << BSHIFT;
    int nCnt = N - n0; if (nCnt > 128) nCnt = 128;
    int lo = bucketStart[b], hi = bucketStart[b + 1];
    int outBase = ((lo + 7) & ~7) + (b << 10);
    int t = threadIdx.x;
    if (t < 128) { cntL[t] = 0; fillL[t] = 0; }
    __syncthreads();
    for (int e = lo + t; e < hi; e += 256)
        atomicAdd(&cntL[ebuf[e] >> 17], 1);
    __syncthreads();
    int pc = 0;
    if (t < 128) { pc = (cntL[t] + 7) & ~7; scanL[t] = pc; }
    __syncthreads();
    for (int off = 1; off < 128; off <<= 1) {
        int u = (t >= off && t < 128) ? scanL[t - off] : 0;
        __syncthreads();
        if (t < 128) scanL[t] += u;
        __syncthreads();
    }
    if (t == 127) padT = scanL[127];
    if (t < nCnt) {
        int ex = scanL[t] - pc;
        row_ptr[n0 + t] = outBase + ex;
        row_blocks[n0 + t] = pc >> 3;
        dinv[n0 + t] = rsqrtf((float)cntL[t] + 1.0f);
        scanL[t] = ex;          // exclusive padded prefix for placement
    }
    __syncthreads();
    int padTotal = padT;
    if (padTotal <= BCAP) {
        for (int i = t; i < padTotal; i += 256) colL[i] = N;   // phantom fill
        __syncthreads();
        for (int e = lo + t; e < hi; e += 256) {
            unsigned int pr = ebuf[e];
            int d = pr >> 17;
            int r = scanL[d] + atomicAdd(&fillL[d], 1);
            colL[r] = (int)(pr & 0x1FFFFu);
        }
        __syncthreads();
        for (int i = t; i < padTotal; i += 256) col[outBase + i] = colL[i];
    } else {                    // fallback (statistically unreachable)
        for (int e = lo + t; e < hi; e += 256) {
            unsigned int pr = ebuf[e];
            int d = pr >> 17;
            int r = scanL[d] + atomicAdd(&fillL[d], 1);
            col[outBase + r] = (int)(pr & 0x1FFFFu);
        }
        __syncthreads();
        if (t < nCnt) {
            int pcl = (cntL[t] + 7) & ~7;
            for (int i = cntL[t]; i < pcl; i++) col[outBase + scanL[t] + i] = N;
        }
    }
}

// Graph boundaries from sorted batch: gstart[g] = first node of graph g; gstart[G]=N.
__global__ void k_bounds(const int* __restrict__ batch, int N, int G, int* __restrict__ gstart) {
    int i = blockIdx.x * blockDim.x + threadIdx.x;
    if (i >= N) return;
    int b = batch[i];
    if (i == 0) { for (int g = 0; g <= b; g++) gstart[g] = 0; }
    else {
        int p = batch[i - 1];
        for (int g = p + 1; g <= b; g++) gstart[g] = i;
    }
    if (i == N - 1) { for (int g = b + 1; g <= G; g++) gstart[g] = N; }
}

// Gb[n,:] = bf16( dinv[n] * (X[n,:] @ W) ), plus phantom row N zeroed (ws is
// re-poisoned every launch). launch_bounds(256,4): cap VGPR (r5: 236->9% occ).
__global__ __launch_bounds__(256, 4) void k_gemm_scale(const float* __restrict__ X,
                                                       const float* __restrict__ W,
                                                       const float* __restrict__ dinv, int N,
                                                       unsigned short* __restrict__ Gb) {
    __shared__ float4 Ws[64 * 16];
    __shared__ float Xs[64][68];
    int tid = threadIdx.x;
    ushort4* GB4 = (ushort4*)Gb;
    if (blockIdx.x == 0 && tid < 16) {      // phantom row N = zeros
        ushort4 z; z.x = z.y = z.z = z.w = 0;
        GB4[(size_t)N * 16 + tid] = z;
    }
    const float4* W4 = (const float4*)W;
    for (int i = tid; i < 64 * 16; i += 256) Ws[i] = W4[i];
    int rowBase = blockIdx.x * 64;
    for (int i = tid; i < 1024; i += 256) {
        int r = i >> 4, f4 = i & 15;
        float4 v = make_float4(0.f, 0.f, 0.f, 0.f);
        if (rowBase + r < N) v = ((const float4*)X)[(size_t)(rowBase + r) * 16 + f4];
        *(float4*)&Xs[r][f4 * 4] = v;
    }
    __syncthreads();
    int r0 = (tid >> 4) * 4;
    int c4 = tid & 15;
    float4 acc0 = make_float4(0,0,0,0), acc1 = acc0, acc2 = acc0, acc3 = acc0;
#pragma unroll 16
    for (int k = 0; k < 64; k++) {
        float4 w = Ws[k * 16 + c4];
        float x0 = Xs[r0 + 0][k], x1 = Xs[r0 + 1][k], x2 = Xs[r0 + 2][k], x3 = Xs[r0 + 3][k];
        acc0.x += x0 * w.x; acc0.y += x0 * w.y; acc0.z += x0 * w.z; acc0.w += x0 * w.w;
        acc1.x += x1 * w.x; acc1.y += x1 * w.y; acc1.z += x1 * w.z; acc1.w += x1 * w.w;
        acc2.x += x2 * w.x; acc2.y += x2 * w.y; acc2.z += x2 * w.z; acc2.w += x2 * w.w;
        acc3.x += x3 * w.x; acc3.y += x3 * w.y; acc3.z += x3 * w.z; acc3.w += x3 * w.w;
    }
    float4 a[4] = {acc0, acc1, acc2, acc3};
#pragma unroll
    for (int i = 0; i < 4; i++) {
        int row = rowBase + r0 + i;
        if (row < N) {
            float dn = dinv[row];
            ushort4 pk;
            pk.x = f2bf(a[i].x * dn);
            pk.y = f2bf(a[i].y * dn);
            pk.z = f2bf(a[i].z * dn);
            pk.w = f2bf(a[i].w * dn);
            GB4[(size_t)row * 16 + c4] = pk;
        }
    }
}

// One node per wave; lane = feature. Rows padded to 8-multiples (phantom N =
// zero row): unconditional loop. col broadcast-loaded as int4; indices moved
// to SGPRs so the gather base computes in SALU.
__global__ __launch_bounds__(256) void k_agg(const unsigned short* __restrict__ Gb,
                                             const int* __restrict__ row_ptr,
                                             const int* __restrict__ row_blocks,
                                             const int* __restrict__ col,
                                             const float* __restrict__ dinv,
                                             const float* __restrict__ bias, int N,
                                             float* __restrict__ Out) {
    int w = threadIdx.x >> 6;
    int c = threadIdx.x & 63;
    int n = blockIdx.x * 4 + w;
    if (n >= N) return;
    int e = row_ptr[n];
    int nb8 = row_blocks[n];
    float acc = bf2f(Gb[(size_t)n * FDIM + c]);
    for (int i = 0; i < nb8; i++, e += 8) {
        int4 ca = *(const int4*)(col + e);
        int4 cb = *(const int4*)(col + e + 4);
        int s0 = __builtin_amdgcn_readfirstlane(ca.x);
        int s1 = __builtin_amdgcn_readfirstlane(ca.y);
        int s2 = __builtin_amdgcn_readfirstlane(ca.z);
        int s3 = __builtin_amdgcn_readfirstlane(ca.w);
        int s4 = __builtin_amdgcn_readfirstlane(cb.x);
        int s5 = __builtin_amdgcn_readfirstlane(cb.y);
        int s6 = __builtin_amdgcn_readfirstlane(cb.z);
        int s7 = __builtin_amdgcn_readfirstlane(cb.w);
        float a0 = bf2f(Gb[(size_t)s0 * FDIM + c]);
        float a1 = bf2f(Gb[(size_t)s1 * FDIM + c]);
        float a2 = bf2f(Gb[(size_t)s2 * FDIM + c]);
        float a3 = bf2f(Gb[(size_t)s3 * FDIM + c]);
        float a4 = bf2f(Gb[(size_t)s4 * FDIM + c]);
        float a5 = bf2f(Gb[(size_t)s5 * FDIM + c]);
        float a6 = bf2f(Gb[(size_t)s6 * FDIM + c]);
        float a7 = bf2f(Gb[(size_t)s7 * FDIM + c]);
        acc += ((a0 + a1) + (a2 + a3)) + ((a4 + a5) + (a6 + a7));
    }
    float v = fmaxf(acc * dinv[n] + bias[c], 0.f);
    Out[(size_t)n * FDIM + c] = v;
}

// One block per graph: segment-sum rows [gstart[g], gstart[g+1]) into pool row.
__global__ __launch_bounds__(256) void k_pool(const float4* __restrict__ H,
                                              const int* __restrict__ gstart,
                                              float* __restrict__ pool, int colOff) {
    int g = blockIdx.x;
    int lo = gstart[g], hi = gstart[g + 1];
    int c4 = threadIdx.x & 15;
    int rl = threadIdx.x >> 4;
    float4 acc = make_float4(0.f, 0.f, 0.f, 0.f);
    for (int r = lo + rl; r < hi; r += 16) {
        float4 v = H[(size_t)r * 16 + c4];
        acc.x += v.x; acc.y += v.y; acc.z += v.z; acc.w += v.w;
    }
    __shared__ float4 sm[16][16];
    sm[rl][c4] = acc;
    __syncthreads();
    if (rl == 0) {
        float4 s = sm[0][c4];
#pragma unroll
        for (int k = 1; k < 16; k++) {
            float4 v = sm[k][c4];
            s.x += v.x; s.y += v.y; s.z += v.z; s.w += v.w;
        }
        float* dst = &pool[(size_t)g * 128 + colOff + c4 * 4];
        dst[0] = s.x; dst[1] = s.y; dst[2] = s.z; dst[3] = s.w;
    }
}

static inline size_t align256(size_t x) { return (x + 255) & ~(size_t)255; }

extern "C" void kernel_launch(void* const* d_in, const int* in_sizes, int n_in,
                              void* d_out, int out_size, void* d_ws, size_t ws_size,
                              hipStream_t stream) {
    const float* x     = (const float*)d_in[0];
    const int*   ei    = (const int*)d_in[1];
    const int*   batch = (const int*)d_in[2];
    const float* W1    = (const float*)d_in[3];
    const float* b1    = (const float*)d_in[4];
    const float* W2    = (const float*)d_in[5];
    const float* b2    = (const float*)d_in[6];

    const int N = in_sizes[0] / FDIM;
    const int E = in_sizes[1] / 2;
    const int G = 64;
    const int NB = (N + 127) >> BSHIFT;   // buckets of 128 nodes
    const int* src = ei;
    const int* dst = ei + E;

    char* p = (char*)d_ws;
    int* row_ptr     = (int*)p; p += align256(((size_t)N + 1) * 4);
    int* row_blocks  = (int*)p; p += align256((size_t)N * 4);
    int* col         = (int*)p; p += align256(((size_t)E + (size_t)(NB + 1) * 1024) * 4);
    int* bucketCnt   = (int*)p; p += align256((size_t)MAXNB * 4);
    int* bucketStart = (int*)p; p += align256((size_t)(MAXNB + 1) * 4);
    int* bucketFill  = (int*)p; p += align256((size_t)MAXNB * 4);
    int* gstart      = (int*)p; p += align256((size_t)(G + 1) * 4);
    float* dinv      = (float*)p; p += align256((size_t)N * 4);
    float* g         = (float*)p; p += align256(((size_t)N + 1) * FDIM * 4); // ebuf then bf16 g(+phantom)
    float* h1        = (float*)p; p += align256((size_t)N * FDIM * 4);
    unsigned int* ebuf = (unsigned int*)g;    // 4.8MB, consumed by k_bsort before GEMM writes g
    unsigned short* gb = (unsigned short*)g;  // bf16 gather buffer, (N+1)*128B

    float* out  = (float*)d_out;
    float* h2   = out;
    float* pool = out + (size_t)N * FDIM;   // [64,128], fully written by k_pool

    hipMemsetAsync(bucketCnt, 0, (size_t)MAXNB * 4, stream);

    int nb = (N + 255) / 256;
    int gemmB = (N + 63) / 64;
    int aggB  = (N + 3) / 4;
    int scatB = (E + 4095) / 4096;

    k_hist<<<256, 256, 0, stream>>>(dst, E, NB, bucketCnt);
    k_bscan<<<1, 1024, 0, stream>>>(bucketCnt, NB, E, bucketStart, bucketFill);
    k_bscat<<<scatB, 256, 0, stream>>>(src, dst, E, NB, bucketFill, ebuf);
    k_bsort<<<NB, 256, 0, stream>>>(ebuf, bucketStart, N, row_ptr, row_blocks, col, dinv);
    k_bounds<<<nb, 256, 0, stream>>>(batch, N, G, gstart);

    // Layer 1
    k_gemm_scale<<<gemmB, 256, 0, stream>>>(x, W1, dinv, N, gb);
    k_agg<<<aggB, 256, 0, stream>>>(gb, row_ptr, row_blocks, col, dinv, b1, N, h1);
    k_pool<<<G, 256, 0, stream>>>((const float4*)h1, gstart, pool, 0);

    // Layer 2
    k_gemm_scale<<<gemmB, 256, 0, stream>>>(h1, W2, dinv, N, gb);
    k_agg<<<aggB, 256, 0, stream>>>(gb, row_ptr, row_blocks, col, dinv, b2, N, h2);
    k_pool<<<G, 256, 0, stream>>>((const float4*)h2, gstart, pool, 64);
}

// Round 9
// 289.841 us; speedup vs baseline: 1.0518x; 1.0518x over previous
//
#include <hip/hip_runtime.h>

// GCN: h1 = relu(GCNConv(x,W1,b1)); s1 = pool(h1); h2 = relu(GCNConv(h1,W2,b2)); s2 = pool(h2)
// out = [h2 (N*64) | per-graph rows [s1(64) s2(64)] (G*128)]
// batch is SORTED -> pooling is contiguous-range segment sum (no atomics).
// CSR build is bucketed (128 nodes/bucket); all random writes stay in LDS.
// Gather buffer g is bf16 (r7: halved k_agg FETCH 147->69MB). CSR rows padded
// to 8-multiples with phantom node N (zero row) -> unconditional gather loop.
// r9: gather loop processes TWO 8-blocks per iteration (16 loads in flight)
// to attack the serial col->gather dependency chain (r8 showed VALU cuts
// don't move k_agg; testing MLP-limit vs fabric-limit).

#define FDIM 64
#define BSHIFT 7                 // 128 nodes per bucket
#define MAXNB 1024               // max buckets supported (N <= 131072)
#define BCAP 4096                // LDS capacity for one bucket's padded col region

__device__ __forceinline__ unsigned short f2bf(float f) {   // RNE
    union { float f; unsigned int u; } a; a.f = f;
    unsigned int u = a.u;
    unsigned int r = u + 0x7fffu + ((u >> 16) & 1u);
    return (unsigned short)(r >> 16);
}
__device__ __forceinline__ float bf2f(unsigned short s) {
    union { unsigned int u; float f; } a; a.u = ((unsigned int)s) << 16;
    return a.f;
}

// ---- pass 1: bucket histogram (blocks 0..255) + graph bounds (blocks 256..) ----
__global__ __launch_bounds__(256) void k_hist(const int* __restrict__ dst, int E, int NB,
                                              int* __restrict__ bucketCnt,
                                              const int* __restrict__ batch, int N, int G,
                                              int* __restrict__ gstart) {
    if (blockIdx.x >= 256) {            // graph boundaries from sorted batch
        int i = (blockIdx.x - 256) * 256 + threadIdx.x;
        if (i >= N) return;
        int b = batch[i];
        if (i == 0) { for (int g = 0; g <= b; g++) gstart[g] = 0; }
        else {
            int p = batch[i - 1];
            for (int g = p + 1; g <= b; g++) gstart[g] = i;
        }
        if (i == N - 1) { for (int g = b + 1; g <= G; g++) gstart[g] = N; }
        return;
    }
    __shared__ int h[MAXNB];
    for (int i = threadIdx.x; i < NB; i += 256) h[i] = 0;
    __syncthreads();
    for (int e = blockIdx.x * blockDim.x + threadIdx.x; e < E; e += 256 * 256)
        atomicAdd(&h[dst[e] >> BSHIFT], 1);
    __syncthreads();
    for (int i = threadIdx.x; i < NB; i += 256) {
        int c = h[i];
        if (c) atomicAdd(&bucketCnt[i], c);
    }
}

// ---- pass 2: scan bucket counts -> bucketStart[NB+1]; init bucketFill ----
__global__ __launch_bounds__(1024) void k_bscan(const int* __restrict__ bucketCnt, int NB, int E,
                                                int* __restrict__ bucketStart,
                                                int* __restrict__ bucketFill) {
    __shared__ int sm[MAXNB];
    int t = threadIdx.x;
    int v = (t < NB) ? bucketCnt[t] : 0;
    sm[t] = v;
    __syncthreads();
    for (int off = 1; off < MAXNB; off <<= 1) {
        int u = (t >= off) ? sm[t - off] : 0;
        __syncthreads();
        sm[t] += u;
        __syncthreads();
    }
    if (t < NB) {
        int ex = sm[t] - v;
        bucketStart[t] = ex;
        bucketFill[t] = ex;
    }
    if (t == 0) bucketStart[NB] = E;
}

// ---- pass 3: scatter packed (dloc<<17 | src) into bucket-grouped ebuf ----
// (src < 2^17 required: N = 100000 fits.)
__global__ __launch_bounds__(256) void k_bscat(const int* __restrict__ src,
                                               const int* __restrict__ dst, int E, int NB,
                                               int* __restrict__ bucketFill,
                                               unsigned int* __restrict__ ebuf) {
    __shared__ int hist[MAXNB];
    __shared__ int base[MAXNB];
    for (int i = threadIdx.x; i < NB; i += 256) hist[i] = 0;
    __syncthreads();
    int e0 = blockIdx.x * 4096;
    int s[16], d[16], r[16];
#pragma unroll
    for (int k = 0; k < 16; k++) {
        int e = e0 + k * 256 + threadIdx.x;
        bool valid = e < E;
        s[k] = valid ? src[e] : 0;
        d[k] = valid ? dst[e] : 0;
        r[k] = valid ? atomicAdd(&hist[d[k] >> BSHIFT], 1) : 0;
    }
    __syncthreads();
    for (int i = threadIdx.x; i < NB; i += 256) {
        int c = hist[i];
        base[i] = c ? atomicAdd(&bucketFill[i], c) : 0;
    }
    __syncthreads();
#pragma unroll
    for (int k = 0; k < 16; k++) {
        int e = e0 + k * 256 + threadIdx.x;
        if (e < E)
            ebuf[base[d[k] >> BSHIFT] + r[k]] =
                (unsigned int)s[k] | ((unsigned int)(d[k] & 127) << 17);
    }
}

// ---- pass 4: per-bucket padded-CSR finalize, entirely in LDS ----
// Each node's col row padded to a multiple of 8 with phantom index N.
// Bucket b's padded region starts at align8(bucketStart[b]) + b*1024
// (max padding/bucket = 128*7 + 7 < 1024, so regions never collide).
__global__ __launch_bounds__(256) void k_bsort(const unsigned int* __restrict__ ebuf,
                                               const int* __restrict__ bucketStart, int N,
                                               int* __restrict__ row_ptr,
                                               int* __restrict__ row_blocks,
                                               int* __restrict__ col,
                                               float* __restrict__ dinv) {
    __shared__ int cntL[128];
    __shared__ int scanL[128];
    __shared__ int fillL[128];
    __shared__ int colL[BCAP];
    __shared__ int padT;
    int b = blockIdx.x;
    int n0 = b << BSHIFT;
    int nCnt = N - n0; if (nCnt > 128) nCnt = 128;
    int lo = bucketStart[b], hi = bucketStart[b + 1];
    int outBase = ((lo + 7) & ~7) + (b << 10);
    int t = threadIdx.x;
    if (t < 128) { cntL[t] = 0; fillL[t] = 0; }
    __syncthreads();
    for (int e = lo + t; e < hi; e += 256)
        atomicAdd(&cntL[ebuf[e] >> 17], 1);
    __syncthreads();
    int pc = 0;
    if (t < 128) { pc = (cntL[t] + 7) & ~7; scanL[t] = pc; }
    __syncthreads();
    for (int off = 1; off < 128; off <<= 1) {
        int u = (t >= off && t < 128) ? scanL[t - off] : 0;
        __syncthreads();
        if (t < 128) scanL[t] += u;
        __syncthreads();
    }
    if (t == 127) padT = scanL[127];
    if (t < nCnt) {
        int ex = scanL[t] - pc;
        row_ptr[n0 + t] = outBase + ex;
        row_blocks[n0 + t] = pc >> 3;
        dinv[n0 + t] = rsqrtf((float)cntL[t] + 1.0f);
        scanL[t] = ex;          // exclusive padded prefix for placement
    }
    __syncthreads();
    int padTotal = padT;
    if (padTotal <= BCAP) {
        for (int i = t; i < padTotal; i += 256) colL[i] = N;   // phantom fill
        __syncthreads();
        for (int e = lo + t; e < hi; e += 256) {
            unsigned int pr = ebuf[e];
            int d = pr >> 17;
            int r = scanL[d] + atomicAdd(&fillL[d], 1);
            colL[r] = (int)(pr & 0x1FFFFu);
        }
        __syncthreads();
        for (int i = t; i < padTotal; i += 256) col[outBase + i] = colL[i];
    } else {                    // fallback (statistically unreachable)
        for (int e = lo + t; e < hi; e += 256) {
            unsigned int pr = ebuf[e];
            int d = pr >> 17;
            int r = scanL[d] + atomicAdd(&fillL[d], 1);
            col[outBase + r] = (int)(pr & 0x1FFFFu);
        }
        __syncthreads();
        if (t < nCnt) {
            int pcl = (cntL[t] + 7) & ~7;
            for (int i = cntL[t]; i < pcl; i++) col[outBase + scanL[t] + i] = N;
        }
    }
}

// Gb[n,:] = bf16( dinv[n] * (X[n,:] @ W) ), plus phantom row N zeroed (ws is
// re-poisoned every launch). launch_bounds(256,4): cap VGPR (r5: 236->9% occ).
__global__ __launch_bounds__(256, 4) void k_gemm_scale(const float* __restrict__ X,
                                                       const float* __restrict__ W,
                                                       const float* __restrict__ dinv, int N,
                                                       unsigned short* __restrict__ Gb) {
    __shared__ float4 Ws[64 * 16];
    __shared__ float Xs[64][68];
    int tid = threadIdx.x;
    ushort4* GB4 = (ushort4*)Gb;
    if (blockIdx.x == 0 && tid < 16) {      // phantom row N = zeros
        ushort4 z; z.x = z.y = z.z = z.w = 0;
        GB4[(size_t)N * 16 + tid] = z;
    }
    const float4* W4 = (const float4*)W;
    for (int i = tid; i < 64 * 16; i += 256) Ws[i] = W4[i];
    int rowBase = blockIdx.x * 64;
    for (int i = tid; i < 1024; i += 256) {
        int r = i >> 4, f4 = i & 15;
        float4 v = make_float4(0.f, 0.f, 0.f, 0.f);
        if (rowBase + r < N) v = ((const float4*)X)[(size_t)(rowBase + r) * 16 + f4];
        *(float4*)&Xs[r][f4 * 4] = v;
    }
    __syncthreads();
    int r0 = (tid >> 4) * 4;
    int c4 = tid & 15;
    float4 acc0 = make_float4(0,0,0,0), acc1 = acc0, acc2 = acc0, acc3 = acc0;
#pragma unroll 16
    for (int k = 0; k < 64; k++) {
        float4 w = Ws[k * 16 + c4];
        float x0 = Xs[r0 + 0][k], x1 = Xs[r0 + 1][k], x2 = Xs[r0 + 2][k], x3 = Xs[r0 + 3][k];
        acc0.x += x0 * w.x; acc0.y += x0 * w.y; acc0.z += x0 * w.z; acc0.w += x0 * w.w;
        acc1.x += x1 * w.x; acc1.y += x1 * w.y; acc1.z += x1 * w.z; acc1.w += x1 * w.w;
        acc2.x += x2 * w.x; acc2.y += x2 * w.y; acc2.z += x2 * w.z; acc2.w += x2 * w.w;
        acc3.x += x3 * w.x; acc3.y += x3 * w.y; acc3.z += x3 * w.z; acc3.w += x3 * w.w;
    }
    float4 a[4] = {acc0, acc1, acc2, acc3};
#pragma unroll
    for (int i = 0; i < 4; i++) {
        int row = rowBase + r0 + i;
        if (row < N) {
            float dn = dinv[row];
            ushort4 pk;
            pk.x = f2bf(a[i].x * dn);
            pk.y = f2bf(a[i].y * dn);
            pk.z = f2bf(a[i].z * dn);
            pk.w = f2bf(a[i].w * dn);
            GB4[(size_t)row * 16 + c4] = pk;
        }
    }
}

// One node per wave; lane = feature. Rows padded to 8-multiples (phantom N =
// zero row). Main loop: TWO 8-blocks per iteration -> one col fetch (8 ints)
// feeds 16 concurrent 128B gathers. Indices scalarized via readfirstlane.
__global__ __launch_bounds__(256) void k_agg(const unsigned short* __restrict__ Gb,
                                             const int* __restrict__ row_ptr,
                                             const int* __restrict__ row_blocks,
                                             const int* __restrict__ col,
                                             const float* __restrict__ dinv,
                                             const float* __restrict__ bias, int N,
                                             float* __restrict__ Out) {
    int w = threadIdx.x >> 6;
    int c = threadIdx.x & 63;
    int n = blockIdx.x * 4 + w;
    if (n >= N) return;
    int e = row_ptr[n];
    int nb8 = row_blocks[n];
    float acc = bf2f(Gb[(size_t)n * FDIM + c]);
    for (; nb8 >= 2; nb8 -= 2, e += 16) {
        int4 ca = *(const int4*)(col + e);
        int4 cb = *(const int4*)(col + e + 4);
        int4 cc = *(const int4*)(col + e + 8);
        int4 cd = *(const int4*)(col + e + 12);
        int s0  = __builtin_amdgcn_readfirstlane(ca.x);
        int s1  = __builtin_amdgcn_readfirstlane(ca.y);
        int s2  = __builtin_amdgcn_readfirstlane(ca.z);
        int s3  = __builtin_amdgcn_readfirstlane(ca.w);
        int s4  = __builtin_amdgcn_readfirstlane(cb.x);
        int s5  = __builtin_amdgcn_readfirstlane(cb.y);
        int s6  = __builtin_amdgcn_readfirstlane(cb.z);
        int s7  = __builtin_amdgcn_readfirstlane(cb.w);
        int s8  = __builtin_amdgcn_readfirstlane(cc.x);
        int s9  = __builtin_amdgcn_readfirstlane(cc.y);
        int s10 = __builtin_amdgcn_readfirstlane(cc.z);
        int s11 = __builtin_amdgcn_readfirstlane(cc.w);
        int s12 = __builtin_amdgcn_readfirstlane(cd.x);
        int s13 = __builtin_amdgcn_readfirstlane(cd.y);
        int s14 = __builtin_amdgcn_readfirstlane(cd.z);
        int s15 = __builtin_amdgcn_readfirstlane(cd.w);
        float a0  = bf2f(Gb[(size_t)s0  * FDIM + c]);
        float a1  = bf2f(Gb[(size_t)s1  * FDIM + c]);
        float a2  = bf2f(Gb[(size_t)s2  * FDIM + c]);
        float a3  = bf2f(Gb[(size_t)s3  * FDIM + c]);
        float a4  = bf2f(Gb[(size_t)s4  * FDIM + c]);
        float a5  = bf2f(Gb[(size_t)s5  * FDIM + c]);
        float a6  = bf2f(Gb[(size_t)s6  * FDIM + c]);
        float a7  = bf2f(Gb[(size_t)s7  * FDIM + c]);
        float a8  = bf2f(Gb[(size_t)s8  * FDIM + c]);
        float a9  = bf2f(Gb[(size_t)s9  * FDIM + c]);
        float a10 = bf2f(Gb[(size_t)s10 * FDIM + c]);
        float a11 = bf2f(Gb[(size_t)s11 * FDIM + c]);
        float a12 = bf2f(Gb[(size_t)s12 * FDIM + c]);
        float a13 = bf2f(Gb[(size_t)s13 * FDIM + c]);
        float a14 = bf2f(Gb[(size_t)s14 * FDIM + c]);
        float a15 = bf2f(Gb[(size_t)s15 * FDIM + c]);
        acc += (((a0 + a1) + (a2 + a3)) + ((a4 + a5) + (a6 + a7)))
             + (((a8 + a9) + (a10 + a11)) + ((a12 + a13) + (a14 + a15)));
    }
    if (nb8) {
        int4 ca = *(const int4*)(col + e);
        int4 cb = *(const int4*)(col + e + 4);
        int s0 = __builtin_amdgcn_readfirstlane(ca.x);
        int s1 = __builtin_amdgcn_readfirstlane(ca.y);
        int s2 = __builtin_amdgcn_readfirstlane(ca.z);
        int s3 = __builtin_amdgcn_readfirstlane(ca.w);
        int s4 = __builtin_amdgcn_readfirstlane(cb.x);
        int s5 = __builtin_amdgcn_readfirstlane(cb.y);
        int s6 = __builtin_amdgcn_readfirstlane(cb.z);
        int s7 = __builtin_amdgcn_readfirstlane(cb.w);
        float a0 = bf2f(Gb[(size_t)s0 * FDIM + c]);
        float a1 = bf2f(Gb[(size_t)s1 * FDIM + c]);
        float a2 = bf2f(Gb[(size_t)s2 * FDIM + c]);
        float a3 = bf2f(Gb[(size_t)s3 * FDIM + c]);
        float a4 = bf2f(Gb[(size_t)s4 * FDIM + c]);
        float a5 = bf2f(Gb[(size_t)s5 * FDIM + c]);
        float a6 = bf2f(Gb[(size_t)s6 * FDIM + c]);
        float a7 = bf2f(Gb[(size_t)s7 * FDIM + c]);
        acc += ((a0 + a1) + (a2 + a3)) + ((a4 + a5) + (a6 + a7));
    }
    float v = fmaxf(acc * dinv[n] + bias[c], 0.f);
    Out[(size_t)n * FDIM + c] = v;
}

// One block per graph: segment-sum rows [gstart[g], gstart[g+1]) into pool row.
__global__ __launch_bounds__(256) void k_pool(const float4* __restrict__ H,
                                              const int* __restrict__ gstart,
                                              float* __restrict__ pool, int colOff) {
    int g = blockIdx.x;
    int lo = gstart[g], hi = gstart[g + 1];
    int c4 = threadIdx.x & 15;
    int rl = threadIdx.x >> 4;
    float4 acc = make_float4(0.f, 0.f, 0.f, 0.f);
    for (int r = lo + rl; r < hi; r += 16) {
        float4 v = H[(size_t)r * 16 + c4];
        acc.x += v.x; acc.y += v.y; acc.z += v.z; acc.w += v.w;
    }
    __shared__ float4 sm[16][16];
    sm[rl][c4] = acc;
    __syncthreads();
    if (rl == 0) {
        float4 s = sm[0][c4];
#pragma unroll
        for (int k = 1; k < 16; k++) {
            float4 v = sm[k][c4];
            s.x += v.x; s.y += v.y; s.z += v.z; s.w += v.w;
        }
        float* dst = &pool[(size_t)g * 128 + colOff + c4 * 4];
        dst[0] = s.x; dst[1] = s.y; dst[2] = s.z; dst[3] = s.w;
    }
}

static inline size_t align256(size_t x) { return (x + 255) & ~(size_t)255; }

extern "C" void kernel_launch(void* const* d_in, const int* in_sizes, int n_in,
                              void* d_out, int out_size, void* d_ws, size_t ws_size,
                              hipStream_t stream) {
    const float* x     = (const float*)d_in[0];
    const int*   ei    = (const int*)d_in[1];
    const int*   batch = (const int*)d_in[2];
    const float* W1    = (const float*)d_in[3];
    const float* b1    = (const float*)d_in[4];
    const float* W2    = (const float*)d_in[5];
    const float* b2    = (const float*)d_in[6];

    const int N = in_sizes[0] / FDIM;
    const int E = in_sizes[1] / 2;
    const int G = 64;
    const int NB = (N + 127) >> BSHIFT;   // buckets of 128 nodes
    const int* src = ei;
    const int* dst = ei + E;

    char* p = (char*)d_ws;
    int* row_ptr     = (int*)p; p += align256(((size_t)N + 1) * 4);
    int* row_blocks  = (int*)p; p += align256((size_t)N * 4);
    int* col         = (int*)p; p += align256(((size_t)E + (size_t)(NB + 1) * 1024) * 4);
    int* bucketCnt   = (int*)p; p += align256((size_t)MAXNB * 4);
    int* bucketStart = (int*)p; p += align256((size_t)(MAXNB + 1) * 4);
    int* bucketFill  = (int*)p; p += align256((size_t)MAXNB * 4);
    int* gstart      = (int*)p; p += align256((size_t)(G + 1) * 4);
    float* dinv      = (float*)p; p += align256((size_t)N * 4);
    float* g         = (float*)p; p += align256(((size_t)N + 1) * FDIM * 4); // ebuf then bf16 g(+phantom)
    float* h1        = (float*)p; p += align256((size_t)N * FDIM * 4);
    unsigned int* ebuf = (unsigned int*)g;    // 4.8MB, consumed by k_bsort before GEMM writes g
    unsigned short* gb = (unsigned short*)g;  // bf16 gather buffer, (N+1)*128B

    float* out  = (float*)d_out;
    float* h2   = out;
    float* pool = out + (size_t)N * FDIM;   // [64,128], fully written by k_pool

    hipMemsetAsync(bucketCnt, 0, (size_t)MAXNB * 4, stream);

    int nb = (N + 255) / 256;
    int gemmB = (N + 63) / 64;
    int aggB  = (N + 3) / 4;
    int scatB = (E + 4095) / 4096;

    k_hist<<<256 + nb, 256, 0, stream>>>(dst, E, NB, bucketCnt, batch, N, G, gstart);
    k_bscan<<<1, 1024, 0, stream>>>(bucketCnt, NB, E, bucketStart, bucketFill);
    k_bscat<<<scatB, 256, 0, stream>>>(src, dst, E, NB, bucketFill, ebuf);
    k_bsort<<<NB, 256, 0, stream>>>(ebuf, bucketStart, N, row_ptr, row_blocks, col, dinv);

    // Layer 1
    k_gemm_scale<<<gemmB, 256, 0, stream>>>(x, W1, dinv, N, gb);
    k_agg<<<aggB, 256, 0, stream>>>(gb, row_ptr, row_blocks, col, dinv, b1, N, h1);
    k_pool<<<G, 256, 0, stream>>>((const float4*)h1, gstart, pool, 0);

    // Layer 2
    k_gemm_scale<<<gemmB, 256, 0, stream>>>(h1, W2, dinv, N, gb);
    k_agg<<<aggB, 256, 0, stream>>>(gb, row_ptr, row_blocks, col, dinv, b2, N, h2);
    k_pool<<<G, 256, 0, stream>>>((const float4*)h2, gstart, pool, 64);
}

// Round 10
// 262.005 us; speedup vs baseline: 1.1636x; 1.1062x over previous
//
#include <hip/hip_runtime.h>

// GCN: h1 = relu(GCNConv(x,W1,b1)); s1 = pool(h1); h2 = relu(GCNConv(h1,W2,b2)); s2 = pool(h2)
// out = [h2 (N*64) | per-graph rows [s1(64) s2(64)] (G*128)]
// batch is SORTED -> pooling is contiguous-range segment sum (no atomics).
// CSR build is bucketed (128 nodes/bucket); all random writes stay in LDS.
// Gather buffer g is bf16 (r7: halved k_agg FETCH 147->69MB). CSR rows padded
// to 8-multiples with phantom node N (zero row) -> unconditional gather loop;
// 16 gathers in flight per wave (r9: MLP win). r10: dispatch-count reduction
// (12->9): k_bscan folded into k_bscat/k_bsort local scans, pools merged,
// one memset.

#define FDIM 64
#define BSHIFT 7                 // 128 nodes per bucket
#define MAXNB 1024               // max buckets supported (N <= 131072)
#define BCAP 4096                // LDS capacity for one bucket's padded col region

__device__ __forceinline__ unsigned short f2bf(float f) {   // RNE
    union { float f; unsigned int u; } a; a.f = f;
    unsigned int u = a.u;
    unsigned int r = u + 0x7fffu + ((u >> 16) & 1u);
    return (unsigned short)(r >> 16);
}
__device__ __forceinline__ float bf2f(unsigned short s) {
    union { unsigned int u; float f; } a; a.u = ((unsigned int)s) << 16;
    return a.f;
}

// ---- pass 1: bucket histogram (blocks 0..255) + graph bounds (blocks 256..) ----
__global__ __launch_bounds__(256) void k_hist(const int* __restrict__ dst, int E, int NB,
                                              int* __restrict__ bucketCnt,
                                              const int* __restrict__ batch, int N, int G,
                                              int* __restrict__ gstart) {
    if (blockIdx.x >= 256) {            // graph boundaries from sorted batch
        int i = (blockIdx.x - 256) * 256 + threadIdx.x;
        if (i >= N) return;
        int b = batch[i];
        if (i == 0) { for (int g = 0; g <= b; g++) gstart[g] = 0; }
        else {
            int p = batch[i - 1];
            for (int g = p + 1; g <= b; g++) gstart[g] = i;
        }
        if (i == N - 1) { for (int g = b + 1; g <= G; g++) gstart[g] = N; }
        return;
    }
    __shared__ int h[MAXNB];
    for (int i = threadIdx.x; i < NB; i += 256) h[i] = 0;
    __syncthreads();
    for (int e = blockIdx.x * blockDim.x + threadIdx.x; e < E; e += 256 * 256)
        atomicAdd(&h[dst[e] >> BSHIFT], 1);
    __syncthreads();
    for (int i = threadIdx.x; i < NB; i += 256) {
        int c = h[i];
        if (c) atomicAdd(&bucketCnt[i], c);
    }
}

// ---- pass 2: scatter packed (dloc<<17 | src) into bucket-grouped ebuf ----
// Each block recomputes the global exclusive bucket prefix from bucketCnt
// (zero-padded to MAXNB) in LDS, then reserves per-bucket ranges via
// atomicAdd on zero-initialized bucketFill. (src < 2^17: N=100000 fits.)
__global__ __launch_bounds__(256) void k_bscat(const int* __restrict__ src,
                                               const int* __restrict__ dst, int E, int NB,
                                               const int* __restrict__ bucketCnt,
                                               int* __restrict__ bucketFill,
                                               unsigned int* __restrict__ ebuf) {
    __shared__ int hist[MAXNB];
    __shared__ int base[MAXNB];
    __shared__ int sc[256];
    int t = threadIdx.x;
    for (int i = t; i < MAXNB; i += 256) hist[i] = 0;
    __syncthreads();
    int e0 = blockIdx.x * 4096;
    int s[16], d[16], r[16];
#pragma unroll
    for (int k = 0; k < 16; k++) {
        int e = e0 + k * 256 + t;
        bool valid = e < E;
        s[k] = valid ? src[e] : 0;
        d[k] = valid ? dst[e] : 0;
        r[k] = valid ? atomicAdd(&hist[d[k] >> BSHIFT], 1) : 0;
    }
    // global exclusive prefix of bucketCnt -> base[] (4 elems/thread)
    int c0 = bucketCnt[t * 4 + 0], c1 = bucketCnt[t * 4 + 1];
    int c2 = bucketCnt[t * 4 + 2], c3 = bucketCnt[t * 4 + 3];
    int ssum = c0 + c1 + c2 + c3;
    sc[t] = ssum;
    __syncthreads();
    for (int off = 1; off < 256; off <<= 1) {
        int u = (t >= off) ? sc[t - off] : 0;
        __syncthreads();
        sc[t] += u;
        __syncthreads();
    }
    int run = sc[t] - ssum;
    base[t * 4 + 0] = run; run += c0;
    base[t * 4 + 1] = run; run += c1;
    base[t * 4 + 2] = run; run += c2;
    base[t * 4 + 3] = run;
    __syncthreads();
    for (int i = t; i < NB; i += 256) {
        int c = hist[i];
        if (c) base[i] += atomicAdd(&bucketFill[i], c);
    }
    __syncthreads();
#pragma unroll
    for (int k = 0; k < 16; k++) {
        int e = e0 + k * 256 + t;
        if (e < E)
            ebuf[base[d[k] >> BSHIFT] + r[k]] =
                (unsigned int)s[k] | ((unsigned int)(d[k] & 127) << 17);
    }
}

// ---- pass 3: per-bucket padded-CSR finalize, entirely in LDS ----
// Block b computes lo = sum(bucketCnt[0..b)) itself (L2-hot reduce).
// Each node's col row padded to a multiple of 8 with phantom index N.
// Bucket b's padded region starts at align8(lo) + b*1024 (max padding/bucket
// = 128*7 + 7 < 1024, so regions never collide).
__global__ __launch_bounds__(256) void k_bsort(const unsigned int* __restrict__ ebuf,
                                               const int* __restrict__ bucketCnt, int N,
                                               int* __restrict__ row_ptr,
                                               int* __restrict__ row_blocks,
                                               int* __restrict__ col,
                                               float* __restrict__ dinv) {
    __shared__ int cntL[128];
    __shared__ int scanL[128];
    __shared__ int fillL[128];
    __shared__ int colL[BCAP];
    __shared__ int padT;
    __shared__ int red[4];
    int b = blockIdx.x;
    int n0 = b << BSHIFT;
    int nCnt = N - n0; if (nCnt > 128) nCnt = 128;
    int t = threadIdx.x;
    // lo = prefix sum of bucketCnt[0..b)
    int part = 0;
    for (int i = t; i < b; i += 256) part += bucketCnt[i];
    for (int off = 32; off; off >>= 1) part += __shfl_down(part, off);
    if ((t & 63) == 0) red[t >> 6] = part;
    __syncthreads();
    int lo = red[0] + red[1] + red[2] + red[3];
    int hi = lo + bucketCnt[b];
    int outBase = ((lo + 7) & ~7) + (b << 10);
    if (t < 128) { cntL[t] = 0; fillL[t] = 0; }
    __syncthreads();
    for (int e = lo + t; e < hi; e += 256)
        atomicAdd(&cntL[ebuf[e] >> 17], 1);
    __syncthreads();
    int pc = 0;
    if (t < 128) { pc = (cntL[t] + 7) & ~7; scanL[t] = pc; }
    __syncthreads();
    for (int off = 1; off < 128; off <<= 1) {
        int u = (t >= off && t < 128) ? scanL[t - off] : 0;
        __syncthreads();
        if (t < 128) scanL[t] += u;
        __syncthreads();
    }
    if (t == 127) padT = scanL[127];
    if (t < nCnt) {
        int ex = scanL[t] - pc;
        row_ptr[n0 + t] = outBase + ex;
        row_blocks[n0 + t] = pc >> 3;
        dinv[n0 + t] = rsqrtf((float)cntL[t] + 1.0f);
        scanL[t] = ex;          // exclusive padded prefix for placement
    }
    __syncthreads();
    int padTotal = padT;
    if (padTotal <= BCAP) {
        for (int i = t; i < padTotal; i += 256) colL[i] = N;   // phantom fill
        __syncthreads();
        for (int e = lo + t; e < hi; e += 256) {
            unsigned int pr = ebuf[e];
            int d = pr >> 17;
            int r = scanL[d] + atomicAdd(&fillL[d], 1);
            colL[r] = (int)(pr & 0x1FFFFu);
        }
        __syncthreads();
        for (int i = t; i < padTotal; i += 256) col[outBase + i] = colL[i];
    } else {                    // fallback (statistically unreachable)
        for (int e = lo + t; e < hi; e += 256) {
            unsigned int pr = ebuf[e];
            int d = pr >> 17;
            int r = scanL[d] + atomicAdd(&fillL[d], 1);
            col[outBase + r] = (int)(pr & 0x1FFFFu);
        }
        __syncthreads();
        if (t < nCnt) {
            int pcl = (cntL[t] + 7) & ~7;
            for (int i = cntL[t]; i < pcl; i++) col[outBase + scanL[t] + i] = N;
        }
    }
}

// Gb[n,:] = bf16( dinv[n] * (X[n,:] @ W) ), plus phantom row N zeroed (ws is
// re-poisoned every launch). launch_bounds(256,4): cap VGPR (r5: 236->9% occ).
__global__ __launch_bounds__(256, 4) void k_gemm_scale(const float* __restrict__ X,
                                                       const float* __restrict__ W,
                                                       const float* __restrict__ dinv, int N,
                                                       unsigned short* __restrict__ Gb) {
    __shared__ float4 Ws[64 * 16];
    __shared__ float Xs[64][68];
    int tid = threadIdx.x;
    ushort4* GB4 = (ushort4*)Gb;
    if (blockIdx.x == 0 && tid < 16) {      // phantom row N = zeros
        ushort4 z; z.x = z.y = z.z = z.w = 0;
        GB4[(size_t)N * 16 + tid] = z;
    }
    const float4* W4 = (const float4*)W;
    for (int i = tid; i < 64 * 16; i += 256) Ws[i] = W4[i];
    int rowBase = blockIdx.x * 64;
    for (int i = tid; i < 1024; i += 256) {
        int r = i >> 4, f4 = i & 15;
        float4 v = make_float4(0.f, 0.f, 0.f, 0.f);
        if (rowBase + r < N) v = ((const float4*)X)[(size_t)(rowBase + r) * 16 + f4];
        *(float4*)&Xs[r][f4 * 4] = v;
    }
    __syncthreads();
    int r0 = (tid >> 4) * 4;
    int c4 = tid & 15;
    float4 acc0 = make_float4(0,0,0,0), acc1 = acc0, acc2 = acc0, acc3 = acc0;
#pragma unroll 16
    for (int k = 0; k < 64; k++) {
        float4 w = Ws[k * 16 + c4];
        float x0 = Xs[r0 + 0][k], x1 = Xs[r0 + 1][k], x2 = Xs[r0 + 2][k], x3 = Xs[r0 + 3][k];
        acc0.x += x0 * w.x; acc0.y += x0 * w.y; acc0.z += x0 * w.z; acc0.w += x0 * w.w;
        acc1.x += x1 * w.x; acc1.y += x1 * w.y; acc1.z += x1 * w.z; acc1.w += x1 * w.w;
        acc2.x += x2 * w.x; acc2.y += x2 * w.y; acc2.z += x2 * w.z; acc2.w += x2 * w.w;
        acc3.x += x3 * w.x; acc3.y += x3 * w.y; acc3.z += x3 * w.z; acc3.w += x3 * w.w;
    }
    float4 a[4] = {acc0, acc1, acc2, acc3};
#pragma unroll
    for (int i = 0; i < 4; i++) {
        int row = rowBase + r0 + i;
        if (row < N) {
            float dn = dinv[row];
            ushort4 pk;
            pk.x = f2bf(a[i].x * dn);
            pk.y = f2bf(a[i].y * dn);
            pk.z = f2bf(a[i].z * dn);
            pk.w = f2bf(a[i].w * dn);
            GB4[(size_t)row * 16 + c4] = pk;
        }
    }
}

// One node per wave; lane = feature. Rows padded to 8-multiples (phantom N =
// zero row). Main loop: TWO 8-blocks per iteration -> one col fetch (8 ints)
// feeds 16 concurrent 128B gathers. Indices scalarized via readfirstlane.
__global__ __launch_bounds__(256) void k_agg(const unsigned short* __restrict__ Gb,
                                             const int* __restrict__ row_ptr,
                                             const int* __restrict__ row_blocks,
                                             const int* __restrict__ col,
                                             const float* __restrict__ dinv,
                                             const float* __restrict__ bias, int N,
                                             float* __restrict__ Out) {
    int w = threadIdx.x >> 6;
    int c = threadIdx.x & 63;
    int n = blockIdx.x * 4 + w;
    if (n >= N) return;
    int e = row_ptr[n];
    int nb8 = row_blocks[n];
    float acc = bf2f(Gb[(size_t)n * FDIM + c]);
    for (; nb8 >= 2; nb8 -= 2, e += 16) {
        int4 ca = *(const int4*)(col + e);
        int4 cb = *(const int4*)(col + e + 4);
        int4 cc = *(const int4*)(col + e + 8);
        int4 cd = *(const int4*)(col + e + 12);
        int s0  = __builtin_amdgcn_readfirstlane(ca.x);
        int s1  = __builtin_amdgcn_readfirstlane(ca.y);
        int s2  = __builtin_amdgcn_readfirstlane(ca.z);
        int s3  = __builtin_amdgcn_readfirstlane(ca.w);
        int s4  = __builtin_amdgcn_readfirstlane(cb.x);
        int s5  = __builtin_amdgcn_readfirstlane(cb.y);
        int s6  = __builtin_amdgcn_readfirstlane(cb.z);
        int s7  = __builtin_amdgcn_readfirstlane(cb.w);
        int s8  = __builtin_amdgcn_readfirstlane(cc.x);
        int s9  = __builtin_amdgcn_readfirstlane(cc.y);
        int s10 = __builtin_amdgcn_readfirstlane(cc.z);
        int s11 = __builtin_amdgcn_readfirstlane(cc.w);
        int s12 = __builtin_amdgcn_readfirstlane(cd.x);
        int s13 = __builtin_amdgcn_readfirstlane(cd.y);
        int s14 = __builtin_amdgcn_readfirstlane(cd.z);
        int s15 = __builtin_amdgcn_readfirstlane(cd.w);
        float a0  = bf2f(Gb[(size_t)s0  * FDIM + c]);
        float a1  = bf2f(Gb[(size_t)s1  * FDIM + c]);
        float a2  = bf2f(Gb[(size_t)s2  * FDIM + c]);
        float a3  = bf2f(Gb[(size_t)s3  * FDIM + c]);
        float a4  = bf2f(Gb[(size_t)s4  * FDIM + c]);
        float a5  = bf2f(Gb[(size_t)s5  * FDIM + c]);
        float a6  = bf2f(Gb[(size_t)s6  * FDIM + c]);
        float a7  = bf2f(Gb[(size_t)s7  * FDIM + c]);
        float a8  = bf2f(Gb[(size_t)s8  * FDIM + c]);
        float a9  = bf2f(Gb[(size_t)s9  * FDIM + c]);
        float a10 = bf2f(Gb[(size_t)s10 * FDIM + c]);
        float a11 = bf2f(Gb[(size_t)s11 * FDIM + c]);
        float a12 = bf2f(Gb[(size_t)s12 * FDIM + c]);
        float a13 = bf2f(Gb[(size_t)s13 * FDIM + c]);
        float a14 = bf2f(Gb[(size_t)s14 * FDIM + c]);
        float a15 = bf2f(Gb[(size_t)s15 * FDIM + c]);
        acc += (((a0 + a1) + (a2 + a3)) + ((a4 + a5) + (a6 + a7)))
             + (((a8 + a9) + (a10 + a11)) + ((a12 + a13) + (a14 + a15)));
    }
    if (nb8) {
        int4 ca = *(const int4*)(col + e);
        int4 cb = *(const int4*)(col + e + 4);
        int s0 = __builtin_amdgcn_readfirstlane(ca.x);
        int s1 = __builtin_amdgcn_readfirstlane(ca.y);
        int s2 = __builtin_amdgcn_readfirstlane(ca.z);
        int s3 = __builtin_amdgcn_readfirstlane(ca.w);
        int s4 = __builtin_amdgcn_readfirstlane(cb.x);
        int s5 = __builtin_amdgcn_readfirstlane(cb.y);
        int s6 = __builtin_amdgcn_readfirstlane(cb.z);
        int s7 = __builtin_amdgcn_readfirstlane(cb.w);
        float a0 = bf2f(Gb[(size_t)s0 * FDIM + c]);
        float a1 = bf2f(Gb[(size_t)s1 * FDIM + c]);
        float a2 = bf2f(Gb[(size_t)s2 * FDIM + c]);
        float a3 = bf2f(Gb[(size_t)s3 * FDIM + c]);
        float a4 = bf2f(Gb[(size_t)s4 * FDIM + c]);
        float a5 = bf2f(Gb[(size_t)s5 * FDIM + c]);
        float a6 = bf2f(Gb[(size_t)s6 * FDIM + c]);
        float a7 = bf2f(Gb[(size_t)s7 * FDIM + c]);
        acc += ((a0 + a1) + (a2 + a3)) + ((a4 + a5) + (a6 + a7));
    }
    float v = fmaxf(acc * dinv[n] + bias[c], 0.f);
    Out[(size_t)n * FDIM + c] = v;
}

// Both pools in one launch: block = graph (0..63 -> h1/cols[0,64), 64..127 ->
// h2/cols[64,128)). Segment-sum rows [gstart[g], gstart[g+1]) into pool row.
__global__ __launch_bounds__(256) void k_pool(const float4* __restrict__ H1,
                                              const float4* __restrict__ H2,
                                              const int* __restrict__ gstart,
                                              float* __restrict__ pool) {
    int g = blockIdx.x & 63;
    int layer = blockIdx.x >> 6;
    const float4* H = layer ? H2 : H1;
    int colOff = layer ? 64 : 0;
    int lo = gstart[g], hi = gstart[g + 1];
    int c4 = threadIdx.x & 15;
    int rl = threadIdx.x >> 4;
    float4 acc = make_float4(0.f, 0.f, 0.f, 0.f);
    for (int r = lo + rl; r < hi; r += 16) {
        float4 v = H[(size_t)r * 16 + c4];
        acc.x += v.x; acc.y += v.y; acc.z += v.z; acc.w += v.w;
    }
    __shared__ float4 sm[16][16];
    sm[rl][c4] = acc;
    __syncthreads();
    if (rl == 0) {
        float4 s = sm[0][c4];
#pragma unroll
        for (int k = 1; k < 16; k++) {
            float4 v = sm[k][c4];
            s.x += v.x; s.y += v.y; s.z += v.z; s.w += v.w;
        }
        float* dst = &pool[(size_t)g * 128 + colOff + c4 * 4];
        dst[0] = s.x; dst[1] = s.y; dst[2] = s.z; dst[3] = s.w;
    }
}

static inline size_t align256(size_t x) { return (x + 255) & ~(size_t)255; }

extern "C" void kernel_launch(void* const* d_in, const int* in_sizes, int n_in,
                              void* d_out, int out_size, void* d_ws, size_t ws_size,
                              hipStream_t stream) {
    const float* x     = (const float*)d_in[0];
    const int*   ei    = (const int*)d_in[1];
    const int*   batch = (const int*)d_in[2];
    const float* W1    = (const float*)d_in[3];
    const float* b1    = (const float*)d_in[4];
    const float* W2    = (const float*)d_in[5];
    const float* b2    = (const float*)d_in[6];

    const int N = in_sizes[0] / FDIM;
    const int E = in_sizes[1] / 2;
    const int G = 64;
    const int NB = (N + 127) >> BSHIFT;   // buckets of 128 nodes
    const int* src = ei;
    const int* dst = ei + E;

    char* p = (char*)d_ws;
    int* row_ptr     = (int*)p; p += align256(((size_t)N + 1) * 4);
    int* row_blocks  = (int*)p; p += align256((size_t)N * 4);
    int* col         = (int*)p; p += align256(((size_t)E + (size_t)(NB + 1) * 1024) * 4);
    int* bucketCnt   = (int*)p; p += align256((size_t)2 * MAXNB * 4);  // cnt | fill (one memset)
    int* bucketFill  = bucketCnt + MAXNB;
    int* gstart      = (int*)p; p += align256((size_t)(G + 1) * 4);
    float* dinv      = (float*)p; p += align256((size_t)N * 4);
    float* g         = (float*)p; p += align256(((size_t)N + 1) * FDIM * 4); // ebuf then bf16 g(+phantom)
    float* h1        = (float*)p; p += align256((size_t)N * FDIM * 4);
    unsigned int* ebuf = (unsigned int*)g;    // 4.8MB, consumed by k_bsort before GEMM writes g
    unsigned short* gb = (unsigned short*)g;  // bf16 gather buffer, (N+1)*128B

    float* out  = (float*)d_out;
    float* h2   = out;
    float* pool = out + (size_t)N * FDIM;   // [64,128], fully written by k_pool

    hipMemsetAsync(bucketCnt, 0, (size_t)2 * MAXNB * 4, stream);

    int nb = (N + 255) / 256;
    int gemmB = (N + 63) / 64;
    int aggB  = (N + 3) / 4;
    int scatB = (E + 4095) / 4096;

    k_hist<<<256 + nb, 256, 0, stream>>>(dst, E, NB, bucketCnt, batch, N, G, gstart);
    k_bscat<<<scatB, 256, 0, stream>>>(src, dst, E, NB, bucketCnt, bucketFill, ebuf);
    k_bsort<<<NB, 256, 0, stream>>>(ebuf, bucketCnt, N, row_ptr, row_blocks, col, dinv);

    // Layer 1
    k_gemm_scale<<<gemmB, 256, 0, stream>>>(x, W1, dinv, N, gb);
    k_agg<<<aggB, 256, 0, stream>>>(gb, row_ptr, row_blocks, col, dinv, b1, N, h1);

    // Layer 2
    k_gemm_scale<<<gemmB, 256, 0, stream>>>(h1, W2, dinv, N, gb);
    k_agg<<<aggB, 256, 0, stream>>>(gb, row_ptr, row_blocks, col, dinv, b2, N, h2);

    // Both pools
    k_pool<<<2 * G, 256, 0, stream>>>((const float4*)h1, (const float4*)h2, gstart, pool);
}